// Round 1
// 28407.877 us; speedup vs baseline: 1.1321x; 1.1321x over previous
//
#include <hip/hip_runtime.h>
#include <cstdint>
#include <cstddef>

// GRU B=64, T=1024, IN=512, H=1024 — persistent cooperative kernel,
// restructured into 4 INDEPENDENT batch groups (16 rows x 64 blocks each).
// Barriers are per-group (64 arrivals, own cachelines) instead of grid-wide
// (256 arrivals): the old kernel was barrier-latency bound (MfmaUtil 0.77%).
// Each block owns one 16-col tile for z, r, AND h~, so z and h stay in
// registers across phases; rh/h are exchanged via global bf16 arrays.

constexpr int Bb = 64;
constexpr int Tt = 1024;
constexpr int IN = 512;
constexpr int H  = 1024;
constexpr int NBLK = 256;
constexpr int NTHR = 256;
constexpr int NGRP = 4;              // independent batch groups
constexpr int GBLK = NBLK / NGRP;    // 64 blocks per group
constexpr int GB   = Bb / NGRP;      // 16 batch rows per group

typedef float  f32x4  __attribute__((ext_vector_type(4)));
typedef __bf16 bf16x8 __attribute__((ext_vector_type(8)));

__global__ void k_cvt(const float* __restrict__ src, __bf16* __restrict__ dst, int n) {
    int i = blockIdx.x * blockDim.x + threadIdx.x;
    if (i < n) dst[i] = (__bf16)src[i];
}

// Per-group barrier: bar[0]=arrive counter, bar[32]=generation.
// Agent scope keeps correctness independent of block->XCD placement.
__device__ inline void gbar(unsigned* bar) {
    __syncthreads();
    if (threadIdx.x == 0) {
        unsigned* cnt = bar;
        unsigned* gen = bar + 32;
        unsigned g = __hip_atomic_load(gen, __ATOMIC_RELAXED, __HIP_MEMORY_SCOPE_AGENT);
        unsigned a = __hip_atomic_fetch_add(cnt, 1u, __ATOMIC_ACQ_REL, __HIP_MEMORY_SCOPE_AGENT);
        if (a == (unsigned)(GBLK - 1)) {
            __hip_atomic_store(cnt, 0u, __ATOMIC_RELAXED, __HIP_MEMORY_SCOPE_AGENT);
            __hip_atomic_store(gen, g + 1u, __ATOMIC_RELEASE, __HIP_MEMORY_SCOPE_AGENT);
        } else {
            while (__hip_atomic_load(gen, __ATOMIC_RELAXED, __HIP_MEMORY_SCOPE_AGENT) == g) {
                __builtin_amdgcn_s_sleep(1);
            }
            (void)__hip_atomic_load(gen, __ATOMIC_ACQUIRE, __HIP_MEMORY_SCOPE_AGENT);
        }
    }
    __syncthreads();
}

__global__ __launch_bounds__(NTHR, 1) void k_gru(
    __bf16*       __restrict__ h_bf,   // (64,1024) recurrent state, bf16
    __bf16*       __restrict__ rh_bf,  // (64,1024) r*h, bf16
    const __bf16* __restrict__ xbf,    // (64,1024,512)
    const __bf16* __restrict__ Ucat,   // (2048,1024) [Uz;Ur]
    const __bf16* __restrict__ Uhbf,   // (1024,1024)
    const __bf16* __restrict__ Wcat,   // (2048,512)  [Wz;Wr]
    const __bf16* __restrict__ Whbf,   // (1024,512)
    const float*  __restrict__ bz, const float* __restrict__ br,
    const float*  __restrict__ bh,
    const float*  __restrict__ h0,     // (64,1024) fp32 init
    float*        __restrict__ out,    // (64,1024,1024) + h_n tail
    unsigned*     bar)
{
    const int blk  = blockIdx.x;
    const int grp  = blk & (NGRP - 1);   // group (batch rows 16*grp..)
    const int ct   = blk >> 2;           // col-tile 0..63 (cols 16*ct..)
    const int tid  = threadIdx.x;
    const int lane = tid & 63;
    const int wave = tid >> 6;           // 0..3 splits K into quarters
    const int ln   = lane & 15;
    const int quad = lane >> 4;

    unsigned* mybar = bar + grp * 64;    // 256B apart per group

    __shared__ float red[8 * 256];       // 8 KB: [z:4 | r:4] or [h:4] split-K partials

    const int row0 = grp * GB;           // batch row base
    const int c0   = ct * 16;            // output col base

    // K chunk for this wave: logical kk in [s, s+384); kk<1024 -> U/h part,
    // else x/W part with kx = kk-1024.
    const int s  = wave * 384;
    const int eK = s + 384;
    const int uEnd = eK < 1024 ? eK : 1024;
    const int wBeg = s > 1024 ? s - 1024 : 0;
    const int wEnd = eK - 1024;

    // per-thread epilogue element (matches MFMA C layout after LDS reduce)
    const int erl = tid >> 4, ecl = tid & 15;
    const int erow = row0 + erl;
    const int ec   = c0 + ecl;
    float hreg = h0[(size_t)erow * H + ec];   // this thread's h element (fp32)
    float zreg = 0.f;
    const float bzc = bz[ec], brc = br[ec], bhc = bh[ec];

    // t-invariant fragment base pointers
    const __bf16* Ah  = h_bf  + (size_t)(row0 + ln) * H + quad * 8;
    const __bf16* Ar  = rh_bf + (size_t)(row0 + ln) * H + quad * 8;
    const __bf16* Bz  = Ucat  + (size_t)(c0 + ln) * H + quad * 8;
    const __bf16* Br  = Ucat  + (size_t)(H + c0 + ln) * H + quad * 8;
    const __bf16* BzW = Wcat  + (size_t)(c0 + ln) * IN + quad * 8;
    const __bf16* BrW = Wcat  + (size_t)(H + c0 + ln) * IN + quad * 8;
    const __bf16* Bh  = Uhbf  + (size_t)(c0 + ln) * H + quad * 8;
    const __bf16* BhW = Whbf  + (size_t)(c0 + ln) * IN + quad * 8;
    const __bf16* Xb  = xbf   + (size_t)(row0 + ln) * Tt * IN + quad * 8;

    for (int t = 0; t < Tt; ++t) {
        const __bf16* Xt = Xb + (size_t)t * IN;
        // ---------------- Phase A: z,r ----------------
        {
            f32x4 az = {0.f, 0.f, 0.f, 0.f};
            f32x4 ar = {0.f, 0.f, 0.f, 0.f};
            #pragma unroll 4
            for (int kk = s; kk < uEnd; kk += 32) {
                bf16x8 a = *(const bf16x8*)(Ah + kk);   // shared A-frag for z and r
                az = __builtin_amdgcn_mfma_f32_16x16x32_bf16(a, *(const bf16x8*)(Bz + kk), az, 0, 0, 0);
                ar = __builtin_amdgcn_mfma_f32_16x16x32_bf16(a, *(const bf16x8*)(Br + kk), ar, 0, 0, 0);
            }
            #pragma unroll 4
            for (int kx = wBeg; kx < wEnd; kx += 32) {
                bf16x8 a = *(const bf16x8*)(Xt + kx);
                az = __builtin_amdgcn_mfma_f32_16x16x32_bf16(a, *(const bf16x8*)(BzW + kx), az, 0, 0, 0);
                ar = __builtin_amdgcn_mfma_f32_16x16x32_bf16(a, *(const bf16x8*)(BrW + kx), ar, 0, 0, 0);
            }
            float* mz = red + wave * 256;
            float* mr = red + 1024 + wave * 256;
            #pragma unroll
            for (int r = 0; r < 4; ++r) {
                mz[(quad * 4 + r) * 16 + ln] = az[r];
                mr[(quad * 4 + r) * 16 + ln] = ar[r];
            }
            __syncthreads();
            {
                const float zs = red[tid] + red[256 + tid] + red[512 + tid] + red[768 + tid];
                const float rs = red[1024 + tid] + red[1280 + tid] + red[1536 + tid] + red[1792 + tid];
                const float zv = 1.f / (1.f + __expf(-(zs + bzc)));
                const float rv = 1.f / (1.f + __expf(-(rs + brc)));
                zreg = zv;
                rh_bf[(size_t)erow * H + ec] = (__bf16)(rv * hreg);
            }
        }
        gbar(mybar);
        // ---------------- Phase B: h~ and h update ----------------
        {
            f32x4 ah = {0.f, 0.f, 0.f, 0.f};
            #pragma unroll 4
            for (int kk = s; kk < uEnd; kk += 32) {
                ah = __builtin_amdgcn_mfma_f32_16x16x32_bf16(*(const bf16x8*)(Ar + kk),
                                                             *(const bf16x8*)(Bh + kk), ah, 0, 0, 0);
            }
            #pragma unroll 4
            for (int kx = wBeg; kx < wEnd; kx += 32) {
                ah = __builtin_amdgcn_mfma_f32_16x16x32_bf16(*(const bf16x8*)(Xt + kx),
                                                             *(const bf16x8*)(BhW + kx), ah, 0, 0, 0);
            }
            float* mh = red + wave * 256;
            #pragma unroll
            for (int r = 0; r < 4; ++r) mh[(quad * 4 + r) * 16 + ln] = ah[r];
            __syncthreads();
            {
                const float hs = red[tid] + red[256 + tid] + red[512 + tid] + red[768 + tid];
                const float pre = hs + bhc;
                const float ex = __expf(2.f * pre);
                const float ht = 1.f - 2.f / (ex + 1.f);
                const float hn = (1.f - zreg) * hreg + zreg * ht;
                hreg = hn;
                h_bf[(size_t)erow * H + ec] = (__bf16)hn;
                out[((size_t)erow * Tt + t) * H + ec] = hn;
            }
        }
        gbar(mybar);
    }

    // tail: h_n = final h (each thread owns exactly one element)
    out[(size_t)Bb * Tt * H + (size_t)erow * H + ec] = hreg;
}

extern "C" void kernel_launch(void* const* d_in, const int* in_sizes, int n_in,
                              void* d_out, int out_size, void* d_ws, size_t ws_size,
                              hipStream_t stream) {
    const float* x  = (const float*)d_in[0];
    const float* h0 = (const float*)d_in[1];
    const float* Wz = (const float*)d_in[2];
    const float* bz = (const float*)d_in[3];
    const float* Uz = (const float*)d_in[4];
    const float* Wr = (const float*)d_in[5];
    const float* br = (const float*)d_in[6];
    const float* Ur = (const float*)d_in[7];
    const float* Wh = (const float*)d_in[8];
    const float* bh = (const float*)d_in[9];
    const float* Uh = (const float*)d_in[10];
    float* out = (float*)d_out;

    char* p = (char*)d_ws;
    __bf16* xbf  = (__bf16*)p;  p += (size_t)Bb * Tt * IN * 2;
    __bf16* Ucat = (__bf16*)p;  p += (size_t)2 * H * H * 2;
    __bf16* Uhbf = (__bf16*)p;  p += (size_t)H * H * 2;
    __bf16* Wcat = (__bf16*)p;  p += (size_t)2 * H * IN * 2;
    __bf16* Whbf = (__bf16*)p;  p += (size_t)H * IN * 2;
    __bf16* h_bf = (__bf16*)p;  p += (size_t)Bb * H * 2;
    __bf16* rh_bf= (__bf16*)p;  p += (size_t)Bb * H * 2;
    unsigned* bar= (unsigned*)p; p += NGRP * 64 * sizeof(unsigned);

    auto cvt = [&](const float* s, __bf16* d, int n) {
        k_cvt<<<(n + 255) / 256, 256, 0, stream>>>(s, d, n);
    };
    cvt(x,  xbf,  Bb * Tt * IN);
    cvt(Uz, Ucat, H * H);
    cvt(Ur, Ucat + (size_t)H * H, H * H);
    cvt(Uh, Uhbf, H * H);
    cvt(Wz, Wcat, H * IN);
    cvt(Wr, Wcat + (size_t)H * IN, H * IN);
    cvt(Wh, Whbf, H * IN);
    cvt(h0, h_bf, Bb * H);
    hipMemsetAsync(bar, 0, NGRP * 64 * sizeof(unsigned), stream);

    void* args[] = {
        (void*)&h_bf, (void*)&rh_bf, (void*)&xbf,
        (void*)&Ucat, (void*)&Uhbf, (void*)&Wcat, (void*)&Whbf,
        (void*)&bz, (void*)&br, (void*)&bh, (void*)&h0, (void*)&out, (void*)&bar
    };
    hipLaunchCooperativeKernel((const void*)k_gru, dim3(NBLK), dim3(NTHR),
                               args, 0, stream);
}

// Round 2
// 22632.581 us; speedup vs baseline: 1.4210x; 1.2552x over previous
//
#include <hip/hip_runtime.h>
#include <cstdint>
#include <cstddef>

// GRU B=64, T=1024, IN=512, H=1024 — persistent cooperative kernel.
// 4 independent batch groups (16 rows x 64 blocks), per-group barriers.
// Round 2: all 6 weight tiles (144 KB/block) staged in dynamic LDS in
// FRAGMENT ORDER ([kstep][lane][8] -> contiguous 1KB wave reads, zero bank
// conflicts). Round 1 was L2-capacity bound: per-XCD weight working set
// (4.6 MB) > 4 MB L2 -> 19.6 MB/step LLC refill at ~700 GB/s = 27.7 us/step.
// With weights in LDS, per-step global traffic is only h/rh/x (~25 MB -> ~2.5 MB).

constexpr int Bb = 64;
constexpr int Tt = 1024;
constexpr int IN = 512;
constexpr int H  = 1024;
constexpr int NBLK = 256;
constexpr int NTHR = 256;
constexpr int NGRP = 4;              // independent batch groups
constexpr int GBLK = NBLK / NGRP;    // 64 blocks per group
constexpr int GB   = Bb / NGRP;      // 16 batch rows per group

// LDS tile offsets (bf16 elements) in the dynamic region
constexpr int oBz  = 0;              // 32 steps * 512 = 16384
constexpr int oBr  = 16384;
constexpr int oBh  = 32768;
constexpr int oBzW = 49152;          // 16 steps * 512 = 8192
constexpr int oBrW = 57344;
constexpr int oBhW = 65536;
constexpr int DYN_LDS_ELEMS = 73728; // 144 KB
constexpr int DYN_LDS_BYTES = DYN_LDS_ELEMS * 2;

typedef float  f32x4  __attribute__((ext_vector_type(4)));
typedef __bf16 bf16x8 __attribute__((ext_vector_type(8)));

__global__ void k_cvt(const float* __restrict__ src, __bf16* __restrict__ dst, int n) {
    int i = blockIdx.x * blockDim.x + threadIdx.x;
    if (i < n) dst[i] = (__bf16)src[i];
}

// Per-group barrier: bar[0]=arrive counter, bar[32]=generation.
__device__ inline void gbar(unsigned* bar) {
    __syncthreads();
    if (threadIdx.x == 0) {
        unsigned* cnt = bar;
        unsigned* gen = bar + 32;
        unsigned g = __hip_atomic_load(gen, __ATOMIC_RELAXED, __HIP_MEMORY_SCOPE_AGENT);
        unsigned a = __hip_atomic_fetch_add(cnt, 1u, __ATOMIC_ACQ_REL, __HIP_MEMORY_SCOPE_AGENT);
        if (a == (unsigned)(GBLK - 1)) {
            __hip_atomic_store(cnt, 0u, __ATOMIC_RELAXED, __HIP_MEMORY_SCOPE_AGENT);
            __hip_atomic_store(gen, g + 1u, __ATOMIC_RELEASE, __HIP_MEMORY_SCOPE_AGENT);
        } else {
            while (__hip_atomic_load(gen, __ATOMIC_RELAXED, __HIP_MEMORY_SCOPE_AGENT) == g) {
                __builtin_amdgcn_s_sleep(1);
            }
            (void)__hip_atomic_load(gen, __ATOMIC_ACQUIRE, __HIP_MEMORY_SCOPE_AGENT);
        }
    }
    __syncthreads();
}

__global__ __launch_bounds__(NTHR, 1) void k_gru(
    __bf16*       __restrict__ h_bf,   // (64,1024) recurrent state, bf16
    __bf16*       __restrict__ rh_bf,  // (64,1024) r*h, bf16
    const __bf16* __restrict__ xbf,    // (64,1024,512)
    const __bf16* __restrict__ Ucat,   // (2048,1024) [Uz;Ur]
    const __bf16* __restrict__ Uhbf,   // (1024,1024)
    const __bf16* __restrict__ Wcat,   // (2048,512)  [Wz;Wr]
    const __bf16* __restrict__ Whbf,   // (1024,512)
    const float*  __restrict__ bz, const float* __restrict__ br,
    const float*  __restrict__ bh,
    const float*  __restrict__ h0,     // (64,1024) fp32 init
    float*        __restrict__ out,    // (64,1024,1024) + h_n tail
    unsigned*     bar)
{
    extern __shared__ __align__(16) char smem_dyn[];
    __bf16* lds = (__bf16*)smem_dyn;

    const int blk  = blockIdx.x;
    const int grp  = blk & (NGRP - 1);   // group (batch rows 16*grp..)
    const int ct   = blk >> 2;           // col-tile 0..63 (cols 16*ct..)
    const int tid  = threadIdx.x;
    const int lane = tid & 63;
    const int wave = tid >> 6;           // 0..3 splits K into quarters
    const int ln   = lane & 15;
    const int quad = lane >> 4;

    unsigned* mybar = bar + grp * 64;    // 256B apart per group

    __shared__ float red[8 * 256];       // 8 KB split-K partials

    const int row0 = grp * GB;           // batch row base
    const int c0   = ct * 16;            // output col base

    // ---- one-time: stage all 6 weight tiles into LDS in fragment order ----
    // frag (st, l): dst[st*512 + l*8 + j] = src[(c0+(l&15))*K + st*32 + (l>>4)*8 + j]
    {
        auto stage = [&](const __bf16* src, int ldsOff, int K) {
            __bf16* dst = lds + ldsOff;
            const int nch = (16 * K) / 8;          // 16B chunks
            for (int idx = tid; idx < nch; idx += NTHR) {
                const int st = idx >> 6, l = idx & 63;
                bf16x8 v = *(const bf16x8*)(src + (size_t)(l & 15) * K + st * 32 + (l >> 4) * 8);
                *(bf16x8*)(dst + idx * 8) = v;
            }
        };
        stage(Ucat + (size_t)c0 * H,        oBz,  H);
        stage(Ucat + (size_t)(H + c0) * H,  oBr,  H);
        stage(Uhbf + (size_t)c0 * H,        oBh,  H);
        stage(Wcat + (size_t)c0 * IN,       oBzW, IN);
        stage(Wcat + (size_t)(H + c0) * IN, oBrW, IN);
        stage(Whbf + (size_t)c0 * IN,       oBhW, IN);
    }
    __syncthreads();

    // K chunk for this wave: logical kk in [s, s+384); kk<1024 -> U/h part,
    // else x/W part with kx = kk-1024.
    const int s  = wave * 384;
    const int eK = s + 384;
    const int uEnd = eK < 1024 ? eK : 1024;
    const int wBeg = s > 1024 ? s - 1024 : 0;
    const int wEnd = eK - 1024;

    // per-thread epilogue element (matches MFMA C layout after LDS reduce)
    const int erl = tid >> 4, ecl = tid & 15;
    const int erow = row0 + erl;
    const int ec   = c0 + ecl;
    float hreg = h0[(size_t)erow * H + ec];   // this thread's h element (fp32)
    float zreg = 0.f;
    const float bzc = bz[ec], brc = br[ec], bhc = bh[ec];

    // t-invariant global A-side fragment pointers
    const __bf16* Ah = h_bf  + (size_t)(row0 + ln) * H + quad * 8;
    const __bf16* Ar = rh_bf + (size_t)(row0 + ln) * H + quad * 8;
    const __bf16* Xb = xbf   + (size_t)(row0 + ln) * Tt * IN + quad * 8;

    for (int t = 0; t < Tt; ++t) {
        const __bf16* Xt = Xb + (size_t)t * IN;
        // ---------------- Phase A: z,r ----------------
        {
            f32x4 az = {0.f, 0.f, 0.f, 0.f};
            f32x4 ar = {0.f, 0.f, 0.f, 0.f};
            #pragma unroll 4
            for (int kk = s; kk < uEnd; kk += 32) {
                const int fi = (kk >> 5) * 512 + lane * 8;
                bf16x8 a = *(const bf16x8*)(Ah + kk);   // shared A-frag for z and r
                az = __builtin_amdgcn_mfma_f32_16x16x32_bf16(a, *(const bf16x8*)(lds + oBz + fi), az, 0, 0, 0);
                ar = __builtin_amdgcn_mfma_f32_16x16x32_bf16(a, *(const bf16x8*)(lds + oBr + fi), ar, 0, 0, 0);
            }
            #pragma unroll 4
            for (int kx = wBeg; kx < wEnd; kx += 32) {
                const int fi = (kx >> 5) * 512 + lane * 8;
                bf16x8 a = *(const bf16x8*)(Xt + kx);
                az = __builtin_amdgcn_mfma_f32_16x16x32_bf16(a, *(const bf16x8*)(lds + oBzW + fi), az, 0, 0, 0);
                ar = __builtin_amdgcn_mfma_f32_16x16x32_bf16(a, *(const bf16x8*)(lds + oBrW + fi), ar, 0, 0, 0);
            }
            float* mz = red + wave * 256;
            float* mr = red + 1024 + wave * 256;
            #pragma unroll
            for (int r = 0; r < 4; ++r) {
                mz[(quad * 4 + r) * 16 + ln] = az[r];
                mr[(quad * 4 + r) * 16 + ln] = ar[r];
            }
            __syncthreads();
            {
                const float zs = red[tid] + red[256 + tid] + red[512 + tid] + red[768 + tid];
                const float rs = red[1024 + tid] + red[1280 + tid] + red[1536 + tid] + red[1792 + tid];
                const float zv = 1.f / (1.f + __expf(-(zs + bzc)));
                const float rv = 1.f / (1.f + __expf(-(rs + brc)));
                zreg = zv;
                rh_bf[(size_t)erow * H + ec] = (__bf16)(rv * hreg);
            }
        }
        gbar(mybar);
        // ---------------- Phase B: h~ and h update ----------------
        {
            f32x4 ah = {0.f, 0.f, 0.f, 0.f};
            #pragma unroll 4
            for (int kk = s; kk < uEnd; kk += 32) {
                const int fi = (kk >> 5) * 512 + lane * 8;
                ah = __builtin_amdgcn_mfma_f32_16x16x32_bf16(*(const bf16x8*)(Ar + kk),
                                                             *(const bf16x8*)(lds + oBh + fi), ah, 0, 0, 0);
            }
            #pragma unroll 4
            for (int kx = wBeg; kx < wEnd; kx += 32) {
                const int fi = (kx >> 5) * 512 + lane * 8;
                ah = __builtin_amdgcn_mfma_f32_16x16x32_bf16(*(const bf16x8*)(Xt + kx),
                                                             *(const bf16x8*)(lds + oBhW + fi), ah, 0, 0, 0);
            }
            float* mh = red + wave * 256;
            #pragma unroll
            for (int r = 0; r < 4; ++r) mh[(quad * 4 + r) * 16 + ln] = ah[r];
            __syncthreads();
            {
                const float hs = red[tid] + red[256 + tid] + red[512 + tid] + red[768 + tid];
                const float pre = hs + bhc;
                const float ex = __expf(2.f * pre);
                const float ht = 1.f - 2.f / (ex + 1.f);
                const float hn = (1.f - zreg) * hreg + zreg * ht;
                hreg = hn;
                h_bf[(size_t)erow * H + ec] = (__bf16)hn;
                out[((size_t)erow * Tt + t) * H + ec] = hn;
            }
        }
        gbar(mybar);
    }

    // tail: h_n = final h (each thread owns exactly one element)
    out[(size_t)Bb * Tt * H + (size_t)erow * H + ec] = hreg;
}

extern "C" void kernel_launch(void* const* d_in, const int* in_sizes, int n_in,
                              void* d_out, int out_size, void* d_ws, size_t ws_size,
                              hipStream_t stream) {
    const float* x  = (const float*)d_in[0];
    const float* h0 = (const float*)d_in[1];
    const float* Wz = (const float*)d_in[2];
    const float* bz = (const float*)d_in[3];
    const float* Uz = (const float*)d_in[4];
    const float* Wr = (const float*)d_in[5];
    const float* br = (const float*)d_in[6];
    const float* Ur = (const float*)d_in[7];
    const float* Wh = (const float*)d_in[8];
    const float* bh = (const float*)d_in[9];
    const float* Uh = (const float*)d_in[10];
    float* out = (float*)d_out;

    char* p = (char*)d_ws;
    __bf16* xbf  = (__bf16*)p;  p += (size_t)Bb * Tt * IN * 2;
    __bf16* Ucat = (__bf16*)p;  p += (size_t)2 * H * H * 2;
    __bf16* Uhbf = (__bf16*)p;  p += (size_t)H * H * 2;
    __bf16* Wcat = (__bf16*)p;  p += (size_t)2 * H * IN * 2;
    __bf16* Whbf = (__bf16*)p;  p += (size_t)H * IN * 2;
    __bf16* h_bf = (__bf16*)p;  p += (size_t)Bb * H * 2;
    __bf16* rh_bf= (__bf16*)p;  p += (size_t)Bb * H * 2;
    unsigned* bar= (unsigned*)p; p += NGRP * 64 * sizeof(unsigned);

    static bool attr_done = false;
    if (!attr_done) {
        hipFuncSetAttribute((const void*)k_gru,
                            hipFuncAttributeMaxDynamicSharedMemorySize,
                            DYN_LDS_BYTES);
        attr_done = true;
    }

    auto cvt = [&](const float* s, __bf16* d, int n) {
        k_cvt<<<(n + 255) / 256, 256, 0, stream>>>(s, d, n);
    };
    cvt(x,  xbf,  Bb * Tt * IN);
    cvt(Uz, Ucat, H * H);
    cvt(Ur, Ucat + (size_t)H * H, H * H);
    cvt(Uh, Uhbf, H * H);
    cvt(Wz, Wcat, H * IN);
    cvt(Wr, Wcat + (size_t)H * IN, H * IN);
    cvt(Wh, Whbf, H * IN);
    cvt(h0, h_bf, Bb * H);
    hipMemsetAsync(bar, 0, NGRP * 64 * sizeof(unsigned), stream);

    void* args[] = {
        (void*)&h_bf, (void*)&rh_bf, (void*)&xbf,
        (void*)&Ucat, (void*)&Uhbf, (void*)&Wcat, (void*)&Whbf,
        (void*)&bz, (void*)&br, (void*)&bh, (void*)&h0, (void*)&out, (void*)&bar
    };
    hipLaunchCooperativeKernel((const void*)k_gru, dim3(NBLK), dim3(NTHR),
                               args, DYN_LDS_BYTES, stream);
}

// Round 3
// 22421.016 us; speedup vs baseline: 1.4344x; 1.0094x over previous
//
#include <hip/hip_runtime.h>
#include <cstdint>
#include <cstddef>

// GRU B=64, T=1024, IN=512, H=1024 — persistent cooperative kernel.
// 4 independent batch groups (16 rows x 64 blocks), per-group barriers.
// Weights (144 KB/block) live in LDS in fragment order, with each gate's
// U-part (32 k-steps) and W-part (16 k-steps) merged into one [48][512]
// array so the MFMA loop indexes LDS uniformly.
// Round 3: A-side fragments (h / rh / x) are PRELOADED into registers in a
// 12-wide burst before the MFMA chain. After each agent-scope barrier the
// L2 is invalidated, so these loads all miss to LLC (~900 cy); round 2
// exposed that latency ~serially (MfmaUtil 1.08%, step 22 us). One burst
// = one exposed round trip per phase.

constexpr int Bb = 64;
constexpr int Tt = 1024;
constexpr int IN = 512;
constexpr int H  = 1024;
constexpr int NBLK = 256;
constexpr int NTHR = 256;
constexpr int NGRP = 4;              // independent batch groups
constexpr int GBLK = NBLK / NGRP;    // 64 blocks per group
constexpr int GB   = Bb / NGRP;      // 16 batch rows per group

// LDS tile offsets (bf16 elements): three [48][512] arrays (steps 0..31 = U,
// steps 32..47 = W), 24576 elems each.
constexpr int oBZ = 0;
constexpr int oBR = 24576;
constexpr int oBH = 49152;
constexpr int DYN_LDS_ELEMS = 73728; // 144 KB
constexpr int DYN_LDS_BYTES = DYN_LDS_ELEMS * 2;

typedef float  f32x4  __attribute__((ext_vector_type(4)));
typedef __bf16 bf16x8 __attribute__((ext_vector_type(8)));

__global__ void k_cvt(const float* __restrict__ src, __bf16* __restrict__ dst, int n) {
    int i = blockIdx.x * blockDim.x + threadIdx.x;
    if (i < n) dst[i] = (__bf16)src[i];
}

// Per-group barrier: bar[0]=arrive counter, bar[32]=generation.
__device__ inline void gbar(unsigned* bar) {
    __syncthreads();
    if (threadIdx.x == 0) {
        unsigned* cnt = bar;
        unsigned* gen = bar + 32;
        unsigned g = __hip_atomic_load(gen, __ATOMIC_RELAXED, __HIP_MEMORY_SCOPE_AGENT);
        unsigned a = __hip_atomic_fetch_add(cnt, 1u, __ATOMIC_ACQ_REL, __HIP_MEMORY_SCOPE_AGENT);
        if (a == (unsigned)(GBLK - 1)) {
            __hip_atomic_store(cnt, 0u, __ATOMIC_RELAXED, __HIP_MEMORY_SCOPE_AGENT);
            __hip_atomic_store(gen, g + 1u, __ATOMIC_RELEASE, __HIP_MEMORY_SCOPE_AGENT);
        } else {
            while (__hip_atomic_load(gen, __ATOMIC_RELAXED, __HIP_MEMORY_SCOPE_AGENT) == g) {
                __builtin_amdgcn_s_sleep(1);
            }
            (void)__hip_atomic_load(gen, __ATOMIC_ACQUIRE, __HIP_MEMORY_SCOPE_AGENT);
        }
    }
    __syncthreads();
}

__global__ __launch_bounds__(NTHR, 1) void k_gru(
    __bf16*       __restrict__ h_bf,   // (64,1024) recurrent state, bf16
    __bf16*       __restrict__ rh_bf,  // (64,1024) r*h, bf16
    const __bf16* __restrict__ xbf,    // (64,1024,512)
    const __bf16* __restrict__ Ucat,   // (2048,1024) [Uz;Ur]
    const __bf16* __restrict__ Uhbf,   // (1024,1024)
    const __bf16* __restrict__ Wcat,   // (2048,512)  [Wz;Wr]
    const __bf16* __restrict__ Whbf,   // (1024,512)
    const float*  __restrict__ bz, const float* __restrict__ br,
    const float*  __restrict__ bh,
    const float*  __restrict__ h0,     // (64,1024) fp32 init
    float*        __restrict__ out,    // (64,1024,1024) + h_n tail
    unsigned*     bar)
{
    extern __shared__ __align__(16) char smem_dyn[];
    __bf16* lds = (__bf16*)smem_dyn;

    const int blk  = blockIdx.x;
    const int grp  = blk & (NGRP - 1);   // group (batch rows 16*grp..)
    const int ct   = blk >> 2;           // col-tile 0..63 (cols 16*ct..)
    const int tid  = threadIdx.x;
    const int lane = tid & 63;
    const int wave = tid >> 6;           // 0..3 splits K into quarters
    const int ln   = lane & 15;
    const int quad = lane >> 4;

    unsigned* mybar = bar + grp * 64;    // 256B apart per group

    __shared__ float red[8 * 256];       // 8 KB split-K partials

    const int row0 = grp * GB;           // batch row base
    const int c0   = ct * 16;            // output col base

    // ---- one-time: stage weight tiles into LDS in fragment order ----
    // dst[st*512 + l*8 + j] = src[(c0+(l&15))*K + st*32 + (l>>4)*8 + j]
    {
        auto stage = [&](const __bf16* src, int ldsOff, int K, int nsteps) {
            __bf16* dst = lds + ldsOff;
            const int nch = nsteps * 64;           // 16B chunks
            for (int idx = tid; idx < nch; idx += NTHR) {
                const int st = idx >> 6, l = idx & 63;
                bf16x8 v = *(const bf16x8*)(src + (size_t)(l & 15) * K + st * 32 + (l >> 4) * 8);
                *(bf16x8*)(dst + idx * 8) = v;
            }
        };
        stage(Ucat + (size_t)c0 * H,        oBZ,         H,  32);
        stage(Wcat + (size_t)c0 * IN,       oBZ + 16384, IN, 16);
        stage(Ucat + (size_t)(H + c0) * H,  oBR,         H,  32);
        stage(Wcat + (size_t)(H + c0) * IN, oBR + 16384, IN, 16);
        stage(Uhbf + (size_t)c0 * H,        oBH,         H,  32);
        stage(Whbf + (size_t)c0 * IN,       oBH + 16384, IN, 16);
    }
    __syncthreads();

    // K chunk for this wave: 12 fragments, logical kk = s + i*32;
    // kk<1024 -> U/h part, else x/W part at kx = kk-1024.
    const int s = wave * 384;

    // per-thread epilogue element (matches MFMA C layout after LDS reduce)
    const int erl = tid >> 4, ecl = tid & 15;
    const int erow = row0 + erl;
    const int ec   = c0 + ecl;
    float hreg = h0[(size_t)erow * H + ec];   // this thread's h element (fp32)
    float zreg = 0.f;
    const float bzc = bz[ec], brc = br[ec], bhc = bh[ec];

    // t-invariant global A-side fragment pointers
    const __bf16* Ah = h_bf  + (size_t)(row0 + ln) * H + quad * 8;
    const __bf16* Ar = rh_bf + (size_t)(row0 + ln) * H + quad * 8;
    const __bf16* Xb = xbf   + (size_t)(row0 + ln) * Tt * IN + quad * 8;

    for (int t = 0; t < Tt; ++t) {
        const __bf16* Xt = Xb + (size_t)t * IN;
        // ---------------- Phase A: z,r ----------------
        {
            // burst-preload all 12 A-side fragments (one LLC round trip)
            bf16x8 fa[12];
            #pragma unroll
            for (int i = 0; i < 12; ++i) {
                const int kk = s + i * 32;
                const __bf16* p = (kk < 1024) ? (Ah + kk) : (Xt + (kk - 1024));
                fa[i] = *(const bf16x8*)p;
            }
            f32x4 az = {0.f, 0.f, 0.f, 0.f};
            f32x4 ar = {0.f, 0.f, 0.f, 0.f};
            #pragma unroll
            for (int i = 0; i < 12; ++i) {
                const int fi = ((s + i * 32) >> 5) * 512 + lane * 8;
                az = __builtin_amdgcn_mfma_f32_16x16x32_bf16(fa[i], *(const bf16x8*)(lds + oBZ + fi), az, 0, 0, 0);
                ar = __builtin_amdgcn_mfma_f32_16x16x32_bf16(fa[i], *(const bf16x8*)(lds + oBR + fi), ar, 0, 0, 0);
            }
            float* mz = red + wave * 256;
            float* mr = red + 1024 + wave * 256;
            #pragma unroll
            for (int r = 0; r < 4; ++r) {
                mz[(quad * 4 + r) * 16 + ln] = az[r];
                mr[(quad * 4 + r) * 16 + ln] = ar[r];
            }
            __syncthreads();
            {
                const float zs = red[tid] + red[256 + tid] + red[512 + tid] + red[768 + tid];
                const float rs = red[1024 + tid] + red[1280 + tid] + red[1536 + tid] + red[1792 + tid];
                const float zv = 1.f / (1.f + __expf(-(zs + bzc)));
                const float rv = 1.f / (1.f + __expf(-(rs + brc)));
                zreg = zv;
                rh_bf[(size_t)erow * H + ec] = (__bf16)(rv * hreg);
            }
        }
        gbar(mybar);
        // ---------------- Phase B: h~ and h update ----------------
        {
            bf16x8 fb[12];
            #pragma unroll
            for (int i = 0; i < 12; ++i) {
                const int kk = s + i * 32;
                const __bf16* p = (kk < 1024) ? (Ar + kk) : (Xt + (kk - 1024));
                fb[i] = *(const bf16x8*)p;
            }
            f32x4 ah = {0.f, 0.f, 0.f, 0.f};
            #pragma unroll
            for (int i = 0; i < 12; ++i) {
                const int fi = ((s + i * 32) >> 5) * 512 + lane * 8;
                ah = __builtin_amdgcn_mfma_f32_16x16x32_bf16(fb[i], *(const bf16x8*)(lds + oBH + fi), ah, 0, 0, 0);
            }
            float* mh = red + wave * 256;
            #pragma unroll
            for (int r = 0; r < 4; ++r) mh[(quad * 4 + r) * 16 + ln] = ah[r];
            __syncthreads();
            {
                const float hs = red[tid] + red[256 + tid] + red[512 + tid] + red[768 + tid];
                const float pre = hs + bhc;
                const float ex = __expf(2.f * pre);
                const float ht = 1.f - 2.f / (ex + 1.f);
                const float hn = (1.f - zreg) * hreg + zreg * ht;
                hreg = hn;
                h_bf[(size_t)erow * H + ec] = (__bf16)hn;
                __builtin_nontemporal_store(hn, &out[((size_t)erow * Tt + t) * H + ec]);
            }
        }
        gbar(mybar);
    }

    // tail: h_n = final h (each thread owns exactly one element)
    out[(size_t)Bb * Tt * H + (size_t)erow * H + ec] = hreg;
}

extern "C" void kernel_launch(void* const* d_in, const int* in_sizes, int n_in,
                              void* d_out, int out_size, void* d_ws, size_t ws_size,
                              hipStream_t stream) {
    const float* x  = (const float*)d_in[0];
    const float* h0 = (const float*)d_in[1];
    const float* Wz = (const float*)d_in[2];
    const float* bz = (const float*)d_in[3];
    const float* Uz = (const float*)d_in[4];
    const float* Wr = (const float*)d_in[5];
    const float* br = (const float*)d_in[6];
    const float* Ur = (const float*)d_in[7];
    const float* Wh = (const float*)d_in[8];
    const float* bh = (const float*)d_in[9];
    const float* Uh = (const float*)d_in[10];
    float* out = (float*)d_out;

    char* p = (char*)d_ws;
    __bf16* xbf  = (__bf16*)p;  p += (size_t)Bb * Tt * IN * 2;
    __bf16* Ucat = (__bf16*)p;  p += (size_t)2 * H * H * 2;
    __bf16* Uhbf = (__bf16*)p;  p += (size_t)H * H * 2;
    __bf16* Wcat = (__bf16*)p;  p += (size_t)2 * H * IN * 2;
    __bf16* Whbf = (__bf16*)p;  p += (size_t)H * IN * 2;
    __bf16* h_bf = (__bf16*)p;  p += (size_t)Bb * H * 2;
    __bf16* rh_bf= (__bf16*)p;  p += (size_t)Bb * H * 2;
    unsigned* bar= (unsigned*)p; p += NGRP * 64 * sizeof(unsigned);

    static bool attr_done = false;
    if (!attr_done) {
        hipFuncSetAttribute((const void*)k_gru,
                            hipFuncAttributeMaxDynamicSharedMemorySize,
                            DYN_LDS_BYTES);
        attr_done = true;
    }

    auto cvt = [&](const float* s, __bf16* d, int n) {
        k_cvt<<<(n + 255) / 256, 256, 0, stream>>>(s, d, n);
    };
    cvt(x,  xbf,  Bb * Tt * IN);
    cvt(Uz, Ucat, H * H);
    cvt(Ur, Ucat + (size_t)H * H, H * H);
    cvt(Uh, Uhbf, H * H);
    cvt(Wz, Wcat, H * IN);
    cvt(Wr, Wcat + (size_t)H * IN, H * IN);
    cvt(Wh, Whbf, H * IN);
    cvt(h0, h_bf, Bb * H);
    hipMemsetAsync(bar, 0, NGRP * 64 * sizeof(unsigned), stream);

    void* args[] = {
        (void*)&h_bf, (void*)&rh_bf, (void*)&xbf,
        (void*)&Ucat, (void*)&Uhbf, (void*)&Wcat, (void*)&Whbf,
        (void*)&bz, (void*)&br, (void*)&bh, (void*)&h0, (void*)&out, (void*)&bar
    };
    hipLaunchCooperativeKernel((const void*)k_gru, dim3(NBLK), dim3(NTHR),
                               args, DYN_LDS_BYTES, stream);
}